// Round 12
// baseline (123.316 us; speedup 1.0000x reference)
//
#include <hip/hip_runtime.h>

// Guided filter r=5, B=8 C=3 H=W=512 fp32 — single fused kernel, round 18.
// TX=32, TY=16 (grid 16x32x24 = 12,288 blocks, 256 thr): LDS 24,544 B ->
// SIX blocks/CU (24 waves/CU, +50% streams vs r13's 4). Hypothesis test:
// the session's only consistent lever is concurrent-block latency overlap
// (3->4 blocks: -3.4% r8; 4->2: +6% r15); this probes past 4 streams at the
// cost of ~+15% P2a work and L2-absorbed halo re-reads (HBM unchanged).
// All falsified structures avoided (see r17 header); proven bodies kept:
//  - P1: 3 segs 9/9/8 x 52 cols (156 thr), 19-row window = 38 loads in ONE
//    VGPR batch (r11 lesson), runtime row mask (r12 lesson), product stash.
//  - P2a/P2b: single body, runtime i<nout per-lane mask (6 chunks: 5x8 +
//    1x2, c0=8ch keeps PB affine); INTR split block-uniform.
//  - P3: 2 segs x 8 rows (84 thr). P4: 64 thr x 8 outputs, affine b64,
//    x prefetched right after P1 barrier (3 phases of cover).
// Affine LDS: chunk starts multiple of 8 -> PB(c0+d) = PB(c0) + OFFD(d).
// Layout: v4[26][59sw] f4 @0 (24,544 B); ab2[26][47sw] f2 ALIASES v4 @0
// (9,776 B, live after P2a-drain barrier); vab @9,856 (=77*128; 6,016 B,
// disjoint from ab2, inside dead v4). V4STR=59: 236 w/row == 12 mod 32;
// ABSTR=47: 94 w/row == 30 mod 32. Conflict counter remains the multi-word
// access floor (b128 8 words/bank, b64 4/bank).
// __launch_bounds__(256,6): 6 blocks x 4 waves = 24 waves/CU; VGPR ~52 ok.

#define R    5
#define TX   32
#define TY   16
#define IMG  512
#define AROWS (TY + 2 * R)   // 26
#define ACOLS (TX + 2 * R)   // 42
#define XCOLS (TX + 4 * R)   // 52
#define V4STR 59             // float4 row stride (PB(51)=57, +pad)
#define ABSTR 47             // float2 row stride (PB(41)=46, +1)
#define OFF_VAB 9856                             // 77*128 >= ab2's 9,776
#define SMEM_TOTAL (AROWS * V4STR * 16)          // 24,544

#define PB(c)   ((c) + ((c) >> 3))
#define OFFD(d) ((d) + ((d) >> 3))   // PB(c0+d)-PB(c0) when c0%8==0

__device__ __forceinline__ float ccnt(int g) {
    int lo = max(g - R, 0), hi = min(g + R, IMG - 1);
    return (float)(hi - lo + 1);
}

// P2a inner: horizontal 11-sum ring + A,b math. Single body, runtime nout
// (per-lane mask — NO divergent body duplication). INTR is block-uniform.
template <bool INTR>
__device__ __forceinline__ void p2_body(const float4* __restrict__ bp,
                                        float2* pres, int nout, int ax0,
                                        float cy, bool ayok) {
    float4 ring[10];
#pragma unroll
    for (int d = 0; d < 10; ++d) ring[d] = bp[OFFD(d)];
    float sx = 0.f, sy = 0.f, sxy = 0.f, sxx = 0.f;
#pragma unroll
    for (int d = 0; d < 10; ++d) {
        sx += ring[d].x; sy += ring[d].y;
        sxy += ring[d].z; sxx += ring[d].w;
    }
#pragma unroll
    for (int i = 0; i < 8; ++i) {
        if (i < nout) {
            float4 lead = bp[OFFD(10 + i)];
            sx += lead.x; sy += lead.y; sxy += lead.z; sxx += lead.w;
            if (i > 0) {
                float4 o = ring[i - 1];
                sx -= o.x; sy -= o.y; sxy -= o.z; sxx -= o.w;
            }
            float A = 0.f, bb = 0.f;
            if (INTR) {
                const float inv = 1.0f / 121.0f;
                float mx = sx * inv, my = sy * inv;
                float cov = sxy * inv - mx * my;
                float var = sxx * inv - mx * mx;
                A = cov * __builtin_amdgcn_rcpf(var + 0.01f);
                bb = my - A * mx;
            } else {
                const int ax = ax0 + i;
                if (ayok && ((unsigned)ax < (unsigned)IMG)) {
                    float inv = __builtin_amdgcn_rcpf(cy * ccnt(ax));
                    float mx = sx * inv, my = sy * inv;
                    float cov = sxy * inv - mx * my;
                    float var = sxx * inv - mx * mx;
                    A = cov * __builtin_amdgcn_rcpf(var + 0.01f);
                    bb = my - A * mx;
                }
            }
            pres[i] = make_float2(A, bb);
        }
    }
}

__global__ __launch_bounds__(256, 6) void guided_fused(
        const float* __restrict__ x, const float* __restrict__ y,
        float* __restrict__ out) {
    __shared__ __align__(16) unsigned char smem[SMEM_TOTAL];
    float4 (*v4)[V4STR] = (float4(*)[V4STR])smem;
    float2 (*ab2)[ABSTR] = (float2(*)[ABSTR])smem;              // aliases v4
    float2 (*vab)[ABSTR] = (float2(*)[ABSTR])(smem + OFF_VAB);  // disjoint from ab2

    const int plane = blockIdx.z;
    const int tx0 = blockIdx.x * TX;
    const int ty0 = blockIdx.y * TY;
    const int tid = threadIdx.x;
    const size_t pbase = (size_t)plane * IMG * IMG;
    const float* xp = x + pbase;
    const float* yp = y + pbase;
    const bool interior = (tx0 >= 2 * R) && (tx0 + TX + 2 * R - 1 < IMG) &&
                          (ty0 >= 2 * R) && (ty0 + TY + 2 * R - 1 < IMG);

    // ---- P1: vertical 11-sums at 52 cols x 26 A,b-rows. 3 segs (9/9/8).
    // 19-row register window: all 38 loads issue in one batch (VGPR-sized).
    if (tid < 3 * XCOLS) {
        const int seg = tid / XCOLS;
        const int cc  = tid - seg * XCOLS;
        const int r0  = seg * 9;              // 0, 9, 18
        const int gx  = tx0 - 2 * R + cc;
        const int gy0 = ty0 - 2 * R + r0;

        float xv[19], yv[19];
        if (interior) {
            const float* xc = xp + (size_t)gy0 * IMG + gx;
            const float* yc = yp + (size_t)gy0 * IMG + gx;
#pragma unroll
            for (int j = 0; j < 19; ++j) {
                xv[j] = xc[(size_t)j * IMG];
                yv[j] = yc[(size_t)j * IMG];
            }
        } else {
            const bool xok = ((unsigned)gx < (unsigned)IMG);
            const bool rows_ok = (gy0 >= 0) && (gy0 + 18 < IMG);
            if (rows_ok) {
                if (xok) {
                    const float* xc = xp + (size_t)gy0 * IMG + gx;
                    const float* yc = yp + (size_t)gy0 * IMG + gx;
#pragma unroll
                    for (int j = 0; j < 19; ++j) {
                        xv[j] = xc[(size_t)j * IMG];
                        yv[j] = yc[(size_t)j * IMG];
                    }
                } else {
#pragma unroll
                    for (int j = 0; j < 19; ++j) { xv[j] = 0.f; yv[j] = 0.f; }
                }
            } else {
#pragma unroll
                for (int j = 0; j < 19; ++j) {
                    int gy = gy0 + j;
                    bool ok = xok && ((unsigned)gy < (unsigned)IMG);
                    size_t o = (size_t)gy * IMG + gx;
                    xv[j] = ok ? xp[o] : 0.f;
                    yv[j] = ok ? yp[o] : 0.f;
                }
            }
        }
        float sx = 0.f, sy = 0.f, sxy = 0.f, sxx = 0.f;
        float pxy[8], pxx[8];   // trailing-edge product stash (rows 0..7)
#pragma unroll
        for (int j = 0; j < 11; ++j) {
            float mxy = xv[j] * yv[j];
            float mxx = xv[j] * xv[j];
            sx += xv[j]; sy += yv[j];
            sxy += mxy; sxx += mxx;
            if (j < 8) { pxy[j] = mxy; pxx[j] = mxx; }
        }
        float4* wp = &v4[r0][PB(cc)];
        wp[0] = make_float4(sx, sy, sxy, sxx);
#pragma unroll
        for (int s = 1; s < 9; ++s) {
            if (r0 + s < AROWS) {   // seg2 stops at 8 rows
                float xn = xv[s + 10], yn = yv[s + 10];
                sx  += xn - xv[s - 1];
                sy  += yn - yv[s - 1];
                sxy += xn * yn - pxy[s - 1];
                sxx += xn * xn - pxx[s - 1];
                wp[(size_t)s * V4STR] = make_float4(sx, sy, sxy, sxx);
            }
        }
    }
    __syncthreads();

    // ---- x-prefetch for P4, hoisted BEFORE P2a (P2a+P2b+P3 of cover).
    float4 xpa = make_float4(0.f, 0.f, 0.f, 0.f), xpb = xpa;
    size_t obase = 0;
    if (tid < TY * 4) {
        const int oy = tid >> 2;
        const int ch = tid & 3;
        obase = (size_t)(ty0 + oy) * IMG + tx0 + 8 * ch;
        xpa = *reinterpret_cast<const float4*>(&xp[obase]);
        xpb = *reinterpret_cast<const float4*>(&xp[obase + 4]);
    }

    // ---- P2a: horizontal 11-sums -> A,b on 42x26, DEFERRED to registers.
    // 156 threads: chunk ch = tid/26 (0..5), row r = tid%26, c0 = 8ch.
    // Runtime nout (8, or 2 for ch=5) masked per-lane inside ONE body.
    int p2_r = 0, p2_pb0 = 0, p2_nout = 0;
    float2 pres[8];
    if (tid < 6 * AROWS) {
        const int ch = tid / AROWS;
        const int r  = tid - ch * AROWS;
        const int nout = (ch == 5) ? 2 : 8;
        p2_r = r; p2_pb0 = 9 * ch; p2_nout = nout;
        const float4* bp = &v4[r][p2_pb0];
        const int ay = ty0 - R + r;
        const float cy = ccnt(ay);
        const bool ayok = ((unsigned)ay < (unsigned)IMG);
        const int ax0 = tx0 - R + 8 * ch;
        if (interior) p2_body<true >(bp, pres, nout, ax0, cy, ayok);
        else          p2_body<false>(bp, pres, nout, ax0, cy, ayok);
    }
    __syncthreads();   // all v4 reads drained -> safe to overwrite with ab2

    // ---- P2b: write deferred A,b into ab2 (aliases v4 region). Affine,
    // single loop with runtime mask (no divergent duplication).
    if (tid < 6 * AROWS) {
        float2* bw = &ab2[p2_r][p2_pb0];
#pragma unroll
        for (int i = 0; i < 8; ++i) {
            if (i < p2_nout) bw[OFFD(i)] = pres[i];
        }
    }
    __syncthreads();

    // ---- P3: vertical 11-sums of (A,b): 42 cols x 2 segs of 8 rows. Ring.
    if (tid < 2 * ACOLS) {
        const int seg = (tid >= ACOLS) ? 1 : 0;
        const int ac = tid - seg * ACOLS;
        const int r0 = seg * 8;
        const float2* rp = &ab2[r0][PB(ac)];
        float2* wp = &vab[r0][PB(ac)];
        float2 ring[10];
#pragma unroll
        for (int d = 0; d < 10; ++d) ring[d] = rp[(size_t)d * ABSTR];
        float sa = 0.f, sb = 0.f;
#pragma unroll
        for (int d = 0; d < 10; ++d) { sa += ring[d].x; sb += ring[d].y; }
#pragma unroll
        for (int s = 0; s < 8; ++s) {
            float2 lead = rp[(size_t)(10 + s) * ABSTR];
            sa += lead.x; sb += lead.y;
            if (s > 0) {
                float2 o = ring[s - 1];
                sa -= o.x; sb -= o.y;
            }
            wp[(size_t)s * ABSTR] = make_float2(sa, sb);
        }
    }
    __syncthreads();

    // ---- P4: horizontal 11-sums + epilogue. 16 rows x 4 width-8 chunks,
    // 64 threads, 8 outputs each. Affine b64 reads; prefetched x.
    if (tid < TY * 4) {
        const int oy = tid >> 2;
        const int ch = tid & 3;
        const int c0 = 8 * ch;
        const float2* vb = &vab[oy][9 * ch];   // PB(8ch) = 9ch
        float2 ring[10];
#pragma unroll
        for (int d = 0; d < 10; ++d) ring[d] = vb[OFFD(d)];
        float sa = 0.f, sb = 0.f;
#pragma unroll
        for (int d = 0; d < 10; ++d) { sa += ring[d].x; sb += ring[d].y; }
        const float xv[8] = {xpa.x, xpa.y, xpa.z, xpa.w,
                             xpb.x, xpb.y, xpb.z, xpb.w};
        float res[8];
        if (interior) {
#pragma unroll
            for (int i = 0; i < 8; ++i) {
                float2 lead = vb[OFFD(10 + i)];
                sa += lead.x; sb += lead.y;
                if (i > 0) {
                    float2 o = ring[i - 1];
                    sa -= o.x; sb -= o.y;
                }
                const float inv = 1.0f / 121.0f;
                res[i] = (sa * inv) * xv[i] + (sb * inv);
            }
        } else {
            const int gy = ty0 + oy;
            const float cy = ccnt(gy);
#pragma unroll
            for (int i = 0; i < 8; ++i) {
                float2 lead = vb[OFFD(10 + i)];
                sa += lead.x; sb += lead.y;
                if (i > 0) {
                    float2 o = ring[i - 1];
                    sa -= o.x; sb -= o.y;
                }
                float inv = __builtin_amdgcn_rcpf(cy * ccnt(tx0 + c0 + i));
                res[i] = (sa * inv) * xv[i] + (sb * inv);
            }
        }
        *reinterpret_cast<float4*>(&out[pbase + obase]) =
            make_float4(res[0], res[1], res[2], res[3]);
        *reinterpret_cast<float4*>(&out[pbase + obase + 4]) =
            make_float4(res[4], res[5], res[6], res[7]);
    }
}

extern "C" void kernel_launch(void* const* d_in, const int* in_sizes, int n_in,
                              void* d_out, int out_size, void* d_ws, size_t ws_size,
                              hipStream_t stream) {
    const float* x = (const float*)d_in[0];
    const float* y = (const float*)d_in[1];
    float* out = (float*)d_out;

    const int planes = in_sizes[0] / (IMG * IMG);  // 24

    dim3 grid(IMG / TX, IMG / TY, planes);  // 16 x 32 x 24
    guided_fused<<<grid, 256, 0, stream>>>(x, y, out);
}

// Round 13
// 117.820 us; speedup vs baseline: 1.0466x; 1.0466x over previous
//
#include <hip/hip_runtime.h>

// Guided filter r=5, B=8 C=3 H=W=512 fp32 — single fused kernel, round 19.
// = r17 body (tied-best 42.5 us) + XCD-AWARE BLOCK SWIZZLE (the one
// untouched lever: L2 locality).
// Mechanism: default dispatch round-robins blocks across 8 XCDs, so tiles
// sharing halos / P4 x re-reads sit on different L2s -> halo re-reads are
// L3 hits (~2-3x L2 latency). P1's 38-load batch waits on its SLOWEST
// load, so those L3 trips set the phase critical path. Swizzle gives each
// XCD a contiguous span of 768 tiles = EXACTLY 3 planes (x+y = 2 MB/plane
// <= 4 MB L2): all halo and x re-reads become local-L2 hits.
//   lid = blockIdx.x (1D, 6144); newlid = (lid%8)*768 + lid/8;
//   plane = newlid/256; by = (newlid%256)>>3; bx = newlid&7.
// Bijective (6144%8==0). Swizzle is perf-only (G16-safe).
// Structure-space map (falsified, do not revisit): r11/r15/r18 tile-size
// (work vs overlap/HBM), r12 divergent bodies, r14 pair-split, r16
// persistent+reg-pipeline (scratch spill), r18 6-blk/CU (FETCH +53%).
// Body: TY=16/TX=64, 256 thr, LDS 40,352 B -> 4 blocks/CU; all LDS affine;
// P1 3 segs 9/9/8 (19-row window = 38-load single batch) + product stash |
// x-prefetch after P1 barrier | P2a single runtime-masked body -> regs |
// P2b -> ab2 (ALIASES v4 @0) | P3 2x8 rows -> vab @17,280 | P4 128 thr x 8.

#define R    5
#define TX   64
#define TY   16
#define IMG  512
#define AROWS (TY + 2 * R)   // 26
#define ACOLS (TX + 2 * R)   // 74
#define XCOLS (TX + 4 * R)   // 84
#define V4STR 97             // float4 row stride
#define ABSTR 83             // float2 row stride
#define OFF_VAB 17280                            // 135*128 >= ab2's 17,264
#define SMEM_TOTAL (AROWS * V4STR * 16)          // 40,352

#define PB(c)   ((c) + ((c) >> 3))
#define OFFD(d) ((d) + ((d) >> 3))   // PB(c0+d)-PB(c0) when c0%8==0

__device__ __forceinline__ float ccnt(int g) {
    int lo = max(g - R, 0), hi = min(g + R, IMG - 1);
    return (float)(hi - lo + 1);
}

// P2a inner: horizontal 11-sum ring + A,b math. Single body, runtime nout
// (per-lane mask — NO divergent body duplication). INTR is block-uniform.
template <bool INTR>
__device__ __forceinline__ void p2_body(const float4* __restrict__ bp,
                                        float2* pres, int nout, int ax0,
                                        float cy, bool ayok) {
    float4 ring[10];
#pragma unroll
    for (int d = 0; d < 10; ++d) ring[d] = bp[OFFD(d)];
    float sx = 0.f, sy = 0.f, sxy = 0.f, sxx = 0.f;
#pragma unroll
    for (int d = 0; d < 10; ++d) {
        sx += ring[d].x; sy += ring[d].y;
        sxy += ring[d].z; sxx += ring[d].w;
    }
#pragma unroll
    for (int i = 0; i < 10; ++i) {
        if (i < nout) {
            float4 lead = bp[OFFD(10 + i)];
            sx += lead.x; sy += lead.y; sxy += lead.z; sxx += lead.w;
            if (i > 0) {
                float4 o = ring[i - 1];
                sx -= o.x; sy -= o.y; sxy -= o.z; sxx -= o.w;
            }
            float A = 0.f, bb = 0.f;
            if (INTR) {
                const float inv = 1.0f / 121.0f;
                float mx = sx * inv, my = sy * inv;
                float cov = sxy * inv - mx * my;
                float var = sxx * inv - mx * mx;
                A = cov * __builtin_amdgcn_rcpf(var + 0.01f);
                bb = my - A * mx;
            } else {
                const int ax = ax0 + i;
                if (ayok && ((unsigned)ax < (unsigned)IMG)) {
                    float inv = __builtin_amdgcn_rcpf(cy * ccnt(ax));
                    float mx = sx * inv, my = sy * inv;
                    float cov = sxy * inv - mx * my;
                    float var = sxx * inv - mx * mx;
                    A = cov * __builtin_amdgcn_rcpf(var + 0.01f);
                    bb = my - A * mx;
                }
            }
            pres[i] = make_float2(A, bb);
        }
    }
}

__global__ __launch_bounds__(256, 4) void guided_fused(
        const float* __restrict__ x, const float* __restrict__ y,
        float* __restrict__ out) {
    __shared__ __align__(16) unsigned char smem[SMEM_TOTAL];
    float4 (*v4)[V4STR] = (float4(*)[V4STR])smem;
    float2 (*ab2)[ABSTR] = (float2(*)[ABSTR])smem;              // aliases v4
    float2 (*vab)[ABSTR] = (float2(*)[ABSTR])(smem + OFF_VAB);  // disjoint from ab2

    // ---- XCD swizzle: contiguous 768-tile span (= 3 planes) per XCD.
    const int lid = blockIdx.x;                  // 0..6143
    const int newlid = (lid & 7) * 768 + (lid >> 3);
    const int plane = newlid >> 8;               // /256 tiles per plane
    const int rem = newlid & 255;
    const int bx = rem & 7;
    const int by = rem >> 3;

    const int tx0 = bx * TX;
    const int ty0 = by * TY;
    const int tid = threadIdx.x;
    const size_t pbase = (size_t)plane * IMG * IMG;
    const float* xp = x + pbase;
    const float* yp = y + pbase;
    const bool interior = (tx0 >= 2 * R) && (tx0 + TX + 2 * R - 1 < IMG) &&
                          (ty0 >= 2 * R) && (ty0 + TY + 2 * R - 1 < IMG);

    // ---- P1: vertical 11-sums at 84 cols x 26 A,b-rows. 3 segs (9/9/8).
    // 19-row register window: all 38 loads issue in one batch (VGPR-sized).
    if (tid < 3 * XCOLS) {
        const int seg = tid / XCOLS;
        const int cc  = tid - seg * XCOLS;
        const int r0  = seg * 9;              // 0, 9, 18
        const int gx  = tx0 - 2 * R + cc;
        const int gy0 = ty0 - 2 * R + r0;

        float xv[19], yv[19];
        if (interior) {
            const float* xc = xp + (size_t)gy0 * IMG + gx;
            const float* yc = yp + (size_t)gy0 * IMG + gx;
#pragma unroll
            for (int j = 0; j < 19; ++j) {
                xv[j] = xc[(size_t)j * IMG];
                yv[j] = yc[(size_t)j * IMG];
            }
        } else {
            const bool xok = ((unsigned)gx < (unsigned)IMG);
            const bool rows_ok = (gy0 >= 0) && (gy0 + 18 < IMG);
            if (rows_ok) {
                if (xok) {
                    const float* xc = xp + (size_t)gy0 * IMG + gx;
                    const float* yc = yp + (size_t)gy0 * IMG + gx;
#pragma unroll
                    for (int j = 0; j < 19; ++j) {
                        xv[j] = xc[(size_t)j * IMG];
                        yv[j] = yc[(size_t)j * IMG];
                    }
                } else {
#pragma unroll
                    for (int j = 0; j < 19; ++j) { xv[j] = 0.f; yv[j] = 0.f; }
                }
            } else {
#pragma unroll
                for (int j = 0; j < 19; ++j) {
                    int gy = gy0 + j;
                    bool ok = xok && ((unsigned)gy < (unsigned)IMG);
                    size_t o = (size_t)gy * IMG + gx;
                    xv[j] = ok ? xp[o] : 0.f;
                    yv[j] = ok ? yp[o] : 0.f;
                }
            }
        }
        float sx = 0.f, sy = 0.f, sxy = 0.f, sxx = 0.f;
        float pxy[8], pxx[8];   // trailing-edge product stash (rows 0..7)
#pragma unroll
        for (int j = 0; j < 11; ++j) {
            float mxy = xv[j] * yv[j];
            float mxx = xv[j] * xv[j];
            sx += xv[j]; sy += yv[j];
            sxy += mxy; sxx += mxx;
            if (j < 8) { pxy[j] = mxy; pxx[j] = mxx; }
        }
        float4* wp = &v4[r0][PB(cc)];
        wp[0] = make_float4(sx, sy, sxy, sxx);
#pragma unroll
        for (int s = 1; s < 9; ++s) {
            if (r0 + s < AROWS) {   // seg2 stops at 8 rows
                float xn = xv[s + 10], yn = yv[s + 10];
                sx  += xn - xv[s - 1];
                sy  += yn - yv[s - 1];
                sxy += xn * yn - pxy[s - 1];
                sxx += xn * xn - pxx[s - 1];
                wp[(size_t)s * V4STR] = make_float4(sx, sy, sxy, sxx);
            }
        }
    }
    __syncthreads();

    // ---- x-prefetch for P4, hoisted BEFORE P2a (P2a+P2b+P3 of cover).
    float4 xpa = make_float4(0.f, 0.f, 0.f, 0.f), xpb = xpa;
    size_t obase = 0;
    if (tid < TY * 8) {
        const int oy = tid >> 3;
        const int ch = tid & 7;
        obase = (size_t)(ty0 + oy) * IMG + tx0 + 8 * ch;
        xpa = *reinterpret_cast<const float4*>(&xp[obase]);
        xpb = *reinterpret_cast<const float4*>(&xp[obase + 4]);
    }

    // ---- P2a: horizontal 11-sums -> A,b on 74x26, DEFERRED to registers.
    // 234 threads: chunk ch = tid/26 (0..8), row r = tid%26, c0 = 8ch.
    // Runtime nout (8, or 10 for ch=8) masked per-lane inside ONE body.
    int p2_r = 0, p2_pb0 = 0, p2_nout = 0;
    float2 pres[10];
    if (tid < 9 * AROWS) {
        const int ch = tid / AROWS;
        const int r  = tid - ch * AROWS;
        const int nout = (ch == 8) ? 10 : 8;
        p2_r = r; p2_pb0 = 9 * ch; p2_nout = nout;
        const float4* bp = &v4[r][p2_pb0];
        const int ay = ty0 - R + r;
        const float cy = ccnt(ay);
        const bool ayok = ((unsigned)ay < (unsigned)IMG);
        const int ax0 = tx0 - R + 8 * ch;
        if (interior) p2_body<true >(bp, pres, nout, ax0, cy, ayok);
        else          p2_body<false>(bp, pres, nout, ax0, cy, ayok);
    }
    __syncthreads();   // all v4 reads drained -> safe to overwrite with ab2

    // ---- P2b: write deferred A,b into ab2 (aliases v4 region). Affine,
    // single loop with runtime mask (no divergent duplication).
    if (tid < 9 * AROWS) {
        float2* bw = &ab2[p2_r][p2_pb0];
#pragma unroll
        for (int i = 0; i < 10; ++i) {
            if (i < p2_nout) bw[OFFD(i)] = pres[i];
        }
    }
    __syncthreads();

    // ---- P3: vertical 11-sums of (A,b): 74 cols x 2 segs of 8 rows. Ring.
    if (tid < 2 * ACOLS) {
        const int seg = (tid >= ACOLS) ? 1 : 0;
        const int ac = tid - seg * ACOLS;
        const int r0 = seg * 8;
        const float2* rp = &ab2[r0][PB(ac)];
        float2* wp = &vab[r0][PB(ac)];
        float2 ring[10];
#pragma unroll
        for (int d = 0; d < 10; ++d) ring[d] = rp[(size_t)d * ABSTR];
        float sa = 0.f, sb = 0.f;
#pragma unroll
        for (int d = 0; d < 10; ++d) { sa += ring[d].x; sb += ring[d].y; }
#pragma unroll
        for (int s = 0; s < 8; ++s) {
            float2 lead = rp[(size_t)(10 + s) * ABSTR];
            sa += lead.x; sb += lead.y;
            if (s > 0) {
                float2 o = ring[s - 1];
                sa -= o.x; sb -= o.y;
            }
            wp[(size_t)s * ABSTR] = make_float2(sa, sb);
        }
    }
    __syncthreads();

    // ---- P4: horizontal 11-sums + epilogue. 16 rows x 8 width-8 chunks,
    // 128 threads, 8 outputs each. Affine b64 reads; prefetched x.
    if (tid < TY * 8) {
        const int oy = tid >> 3;
        const int ch = tid & 7;
        const int c0 = 8 * ch;
        const float2* vb = &vab[oy][9 * ch];   // PB(8ch) = 9ch
        float2 ring[10];
#pragma unroll
        for (int d = 0; d < 10; ++d) ring[d] = vb[OFFD(d)];
        float sa = 0.f, sb = 0.f;
#pragma unroll
        for (int d = 0; d < 10; ++d) { sa += ring[d].x; sb += ring[d].y; }
        const float xv[8] = {xpa.x, xpa.y, xpa.z, xpa.w,
                             xpb.x, xpb.y, xpb.z, xpb.w};
        float res[8];
        if (interior) {
#pragma unroll
            for (int i = 0; i < 8; ++i) {
                float2 lead = vb[OFFD(10 + i)];
                sa += lead.x; sb += lead.y;
                if (i > 0) {
                    float2 o = ring[i - 1];
                    sa -= o.x; sb -= o.y;
                }
                const float inv = 1.0f / 121.0f;
                res[i] = (sa * inv) * xv[i] + (sb * inv);
            }
        } else {
            const int gy = ty0 + oy;
            const float cy = ccnt(gy);
#pragma unroll
            for (int i = 0; i < 8; ++i) {
                float2 lead = vb[OFFD(10 + i)];
                sa += lead.x; sb += lead.y;
                if (i > 0) {
                    float2 o = ring[i - 1];
                    sa -= o.x; sb -= o.y;
                }
                float inv = __builtin_amdgcn_rcpf(cy * ccnt(tx0 + c0 + i));
                res[i] = (sa * inv) * xv[i] + (sb * inv);
            }
        }
        *reinterpret_cast<float4*>(&out[pbase + obase]) =
            make_float4(res[0], res[1], res[2], res[3]);
        *reinterpret_cast<float4*>(&out[pbase + obase + 4]) =
            make_float4(res[4], res[5], res[6], res[7]);
    }
}

extern "C" void kernel_launch(void* const* d_in, const int* in_sizes, int n_in,
                              void* d_out, int out_size, void* d_ws, size_t ws_size,
                              hipStream_t stream) {
    const float* x = (const float*)d_in[0];
    const float* y = (const float*)d_in[1];
    float* out = (float*)d_out;

    const int planes = in_sizes[0] / (IMG * IMG);  // 24

    // 1D grid; XCD swizzle inside the kernel assigns each XCD a contiguous
    // 3-plane span (6144 blocks = 8 XCDs x 768).
    dim3 grid(8 * 32 * planes);
    guided_fused<<<grid, 256, 0, stream>>>(x, y, out);
}